// Round 1
// baseline (473.883 us; speedup 1.0000x reference)
//
#include <hip/hip_runtime.h>
#include <math.h>

#define BB 2
#define LL 2048
#define EE 2048
#define HH 16
#define HD 128
#define N3E (3*EE)   // 6144

typedef __attribute__((ext_vector_type(8))) short  bf16x8;
typedef __attribute__((ext_vector_type(4))) float  f32x4;

__device__ __forceinline__ ushort f2bf(float f) {
    union { float f; unsigned u; } v; v.f = f;
    unsigned u = v.u + 0x7FFFu + ((v.u >> 16) & 1u);   // RNE
    return (ushort)(u >> 16);
}
__device__ __forceinline__ float bf2f(ushort u) {
    union { unsigned u; float f; } v; v.u = ((unsigned)u) << 16;
    return v.f;
}

// ---------------- fp32 -> bf16 convert (x) ----------------
__global__ __launch_bounds__(256) void cvt_bf16(const float* __restrict__ in,
                                                ushort* __restrict__ out, int n) {
    int i = (blockIdx.x * 256 + threadIdx.x) * 8;
    float4 a = *(const float4*)(in + i);
    float4 b = *(const float4*)(in + i + 4);
    ushort4 p0 = { f2bf(a.x), f2bf(a.y), f2bf(a.z), f2bf(a.w) };
    ushort4 p1 = { f2bf(b.x), f2bf(b.y), f2bf(b.z), f2bf(b.w) };
    *(ushort4*)(out + i)     = p0;
    *(ushort4*)(out + i + 4) = p1;
}

// ---------------- fp32 [R][C] -> bf16 [C][R] transpose (weights) ----------------
__global__ __launch_bounds__(256) void transpose_bf16(const float* __restrict__ in,
                                                      ushort* __restrict__ out,
                                                      int R, int Ccol) {
    __shared__ float tile[32][33];
    int c0 = blockIdx.x * 32, r0 = blockIdx.y * 32;
    int t = threadIdx.x;
    int lr = t >> 5, lc = t & 31;
    #pragma unroll
    for (int i = 0; i < 4; ++i)
        tile[lr + i * 8][lc] = in[(size_t)(r0 + lr + i * 8) * Ccol + c0 + lc];
    __syncthreads();
    #pragma unroll
    for (int i = 0; i < 4; ++i)
        out[(size_t)(c0 + lr + i * 8) * R + r0 + lc] = f2bf(tile[lc][lr + i * 8]);
}

// ---------------- bf16 MFMA GEMM (m97 structure, unchanged) ----------------
template<int WRITE_BF16>
__global__ __launch_bounds__(256) void gemm_bt_bf16(const ushort* __restrict__ A,
                                                    const ushort* __restrict__ Bt,
                                                    const float* __restrict__ bias,
                                                    void* __restrict__ C,
                                                    int M, int N, int K) {
    __shared__ __align__(16) ushort As[128 * 32];
    __shared__ __align__(16) ushort Bs[128 * 32];
    const int t    = threadIdx.x;
    const int lane = t & 63, w = t >> 6;
    const int m    = lane & 15, quad = lane >> 4;
    const int wm   = w >> 1, wn = w & 1;
    const int m0   = blockIdx.y * 128, n0 = blockIdx.x * 128;

    f32x4 acc[4][4];
    #pragma unroll
    for (int i = 0; i < 4; ++i)
        #pragma unroll
        for (int j = 0; j < 4; ++j) acc[i][j] = (f32x4){0.f, 0.f, 0.f, 0.f};

    for (int k0 = 0; k0 < K; k0 += 32) {
        __syncthreads();
        #pragma unroll
        for (int i = 0; i < 2; ++i) {
            int c = t + i * 256;
            int row = c >> 2, kc = c & 3;
            __builtin_amdgcn_global_load_lds(
                (const __attribute__((address_space(1))) unsigned int*)(A + (size_t)(m0 + row) * K + k0 + kc * 8),
                (__attribute__((address_space(3))) unsigned int*)(As + c * 8),
                16, 0, 0);
        }
        #pragma unroll
        for (int i = 0; i < 2; ++i) {
            int c = t + i * 256;
            int row = c >> 2, kc = c & 3;
            __builtin_amdgcn_global_load_lds(
                (const __attribute__((address_space(1))) unsigned int*)(Bt + (size_t)(n0 + row) * K + k0 + kc * 8),
                (__attribute__((address_space(3))) unsigned int*)(Bs + c * 8),
                16, 0, 0);
        }
        __syncthreads();
        bf16x8 af[4], bfr[4];
        #pragma unroll
        for (int mt = 0; mt < 4; ++mt)
            af[mt] = *(const bf16x8*)&As[(wm * 64 + mt * 16 + m) * 32 + quad * 8];
        #pragma unroll
        for (int nt = 0; nt < 4; ++nt)
            bfr[nt] = *(const bf16x8*)&Bs[(wn * 64 + nt * 16 + m) * 32 + quad * 8];
        #pragma unroll
        for (int mt = 0; mt < 4; ++mt)
            #pragma unroll
            for (int nt = 0; nt < 4; ++nt)
                acc[mt][nt] = __builtin_amdgcn_mfma_f32_16x16x32_bf16(af[mt], bfr[nt], acc[mt][nt], 0, 0, 0);
    }
    #pragma unroll
    for (int mt = 0; mt < 4; ++mt) {
        #pragma unroll
        for (int nt = 0; nt < 4; ++nt) {
            #pragma unroll
            for (int r = 0; r < 4; ++r) {
                int row = m0 + wm * 64 + mt * 16 + quad * 4 + r;
                int col = n0 + wn * 64 + nt * 16 + m;
                float v = acc[mt][nt][r] + bias[col];
                if (WRITE_BF16) ((ushort*)C)[(size_t)row * N + col] = f2bf(v);
                else            ((float*)C)[(size_t)row * N + col] = v;
            }
        }
    }
}

// ---------------- prep: RoPE + scale + tile/swizzle Q,K ----------------
// Output tiles per (b,h): 32 tiles x [64 rows][16 chunks of 16B], chunk stored
// at physical p holds logical chunk c = p ^ (r&15).  Q gets 1/sqrt(HD) folded.
__global__ __launch_bounds__(256) void prep_qk(const ushort* __restrict__ qkvb,
                                               const int* __restrict__ pos_ids,
                                               ushort* __restrict__ Qt,
                                               ushort* __restrict__ Kt) {
    const float scale = 0.08838834764831845f;
    // -log2(10000)/64
    const float nl2b = -0.20762050593046014f;
    int idx = blockIdx.x * 256 + threadIdx.x;      // B*H*32*64*16 = 1048576
    int p    = idx & 15;
    int r    = (idx >> 4) & 63;
    int tile = (idx >> 10) & 31;
    int h    = (idx >> 15) & 15;
    int b    = idx >> 19;
    int c    = p ^ (r & 15);
    int l    = tile * 64 + r;
    int half = c >> 3, cl = c & 7;
    const ushort* row = qkvb + (size_t)(b * LL + l) * N3E;
    float pos = (float)pos_ids[b * LL + l];

    bf16x8 qa = *(const bf16x8*)(row + h * HD + c * 8);
    bf16x8 qb = *(const bf16x8*)(row + h * HD + (c ^ 8) * 8);
    bf16x8 ka = *(const bf16x8*)(row + EE + h * HD + c * 8);
    bf16x8 kb = *(const bf16x8*)(row + EE + h * HD + (c ^ 8) * 8);
    bf16x8 qo, ko;
    #pragma unroll
    for (int i = 0; i < 8; ++i) {
        int j = cl * 8 + i;
        // 10000^(-j/64) == exp2(j * -log2(10000)/64)  (identical value, no powf)
        float ang = pos * exp2f((float)j * nl2b);
        float s, cs;
        sincosf(ang, &s, &cs);
        float sgn = half ? s : -s;
        float q1 = bf2f((ushort)qa[i]), q2 = bf2f((ushort)qb[i]);
        float k1 = bf2f((ushort)ka[i]), k2 = bf2f((ushort)kb[i]);
        qo[i] = (short)f2bf((q1 * cs + q2 * sgn) * scale);
        ko[i] = (short)f2bf(k1 * cs + k2 * sgn);
    }
    size_t obase = ((size_t)(b * 16 + h) * 32 + tile) * 8192 + r * 128 + p * 8;
    *(bf16x8*)(Qt + obase) = qo;
    *(bf16x8*)(Kt + obase) = ko;
}

// ---------------- prep: V -> V^T tiles ----------------
// Per (b,h): 32 tiles x [128 rows (d)][8 chunks], physical p holds c = p^(r&7).
__global__ __launch_bounds__(256) void prep_v(const ushort* __restrict__ qkvb,
                                              ushort* __restrict__ Vtt) {
    int idx = blockIdx.x * 256 + threadIdx.x;      // B*H*32*128*8 = 1048576
    int p    = idx & 7;
    int r    = (idx >> 3) & 127;                    // d
    int tile = (idx >> 10) & 31;
    int h    = (idx >> 15) & 15;
    int b    = idx >> 19;
    int c    = p ^ (r & 7);
    int col  = 2 * EE + h * HD + r;
    bf16x8 o;
    #pragma unroll
    for (int i = 0; i < 8; ++i) {
        int kk = tile * 64 + c * 8 + i;
        o[i] = (short)qkvb[(size_t)(b * LL + kk) * N3E + col];
    }
    *(bf16x8*)(Vtt + ((size_t)(b * 16 + h) * 32 + tile) * 8192 + r * 64 + p * 8) = o;
}

// ---------------- Flash attention v2: BQ=128, pipelined global_load_lds staging ----------------
// Split-barrier schedule (T3/T4 at 2-phase granularity):
//   B1: vmcnt(0)+s_barrier -> Ks holds K[t]; issue V[t] loads; QK^T+softmax (V hides)
//   B2: vmcnt(0)+s_barrier -> Vs holds V[t], all waves done with Ks; issue K[t+1]; PV (K hides)
#define PSTR 68

__global__ __launch_bounds__(256, 2) void flash2(const ushort* __restrict__ Qt,
                                                 const ushort* __restrict__ Kt,
                                                 const ushort* __restrict__ Vtt,
                                                 ushort* __restrict__ y) {
    __shared__ __align__(16) ushort Ks[64 * 128];    // 16 KB, swizzled tile image
    __shared__ __align__(16) ushort Vs[128 * 64];    // 16 KB
    __shared__ __align__(16) ushort Ps[4 * 32 * PSTR];

    const int t    = threadIdx.x;
    const int w    = t >> 6;
    const int lane = t & 63;
    const int m    = lane & 15;
    const int quad = lane >> 4;
    const int qblk = blockIdx.x;                     // 0..15
    const int bh   = blockIdx.y;
    const int b    = bh >> 4, h = bh & 15;

    const ushort* Qhead = Qt  + (size_t)bh * 32 * 8192;
    const ushort* Khead = Kt  + (size_t)bh * 32 * 8192;
    const ushort* Vhead = Vtt + (size_t)bh * 32 * 8192;

    // ---- Q A-frags direct from global (one-time) ----
    bf16x8 qf[2][4];
    #pragma unroll
    for (int mt = 0; mt < 2; ++mt) {
        int rloc = w * 32 + mt * 16 + m;             // 0..127; rloc&15 == m
        const ushort* qtile = Qhead + (size_t)(qblk * 2 + (rloc >> 6)) * 8192
                              + (rloc & 63) * 128;
        #pragma unroll
        for (int ks = 0; ks < 4; ++ks)
            qf[mt][ks] = *(const bf16x8*)(qtile + ((ks * 4 + quad) ^ m) * 8);
    }

    f32x4 oacc[2][8];
    #pragma unroll
    for (int mt = 0; mt < 2; ++mt)
        #pragma unroll
        for (int dt = 0; dt < 8; ++dt) oacc[mt][dt] = (f32x4){0.f, 0.f, 0.f, 0.f};
    float m_i[8], l_pl[8];
    #pragma unroll
    for (int s = 0; s < 8; ++s) { m_i[s] = -INFINITY; l_pl[s] = 0.f; }

    // ---- prologue: issue K[0] loads (in flight across first B1) ----
    {
        const ushort* ksrc = Khead;
        #pragma unroll
        for (int i = 0; i < 4; ++i) {
            int cid = t + i * 256;
            __builtin_amdgcn_global_load_lds(
                (const __attribute__((address_space(1))) unsigned int*)(ksrc + cid * 8),
                (__attribute__((address_space(3))) unsigned int*)(Ks + cid * 8),
                16, 0, 0);
        }
    }

    for (int kt = 0; kt < 32; ++kt) {
        // B1: K[kt] arrived everywhere; prev-iter PV reads of Vs complete.
        asm volatile("s_waitcnt vmcnt(0)\n\ts_barrier" ::: "memory");

        // issue V[kt] -> Vs (overlaps QK^T + softmax below)
        {
            const ushort* vsrc = Vhead + (size_t)kt * 8192;
            #pragma unroll
            for (int i = 0; i < 4; ++i) {
                int cid = t + i * 256;
                __builtin_amdgcn_global_load_lds(
                    (const __attribute__((address_space(1))) unsigned int*)(vsrc + cid * 8),
                    (__attribute__((address_space(3))) unsigned int*)(Vs + cid * 8),
                    16, 0, 0);
            }
        }

        // ---- S = Q @ K^T : 32 MFMA from 16 K-frag reads ----
        f32x4 sacc[2][4];
        #pragma unroll
        for (int mt = 0; mt < 2; ++mt)
            #pragma unroll
            for (int nt = 0; nt < 4; ++nt) sacc[mt][nt] = (f32x4){0.f, 0.f, 0.f, 0.f};
        __builtin_amdgcn_s_setprio(1);
        #pragma unroll
        for (int ks = 0; ks < 4; ++ks) {
            #pragma unroll
            for (int nt = 0; nt < 4; ++nt) {
                bf16x8 kf = *(const bf16x8*)&Ks[(nt * 16 + m) * 128 + (((ks * 4 + quad) ^ m)) * 8];
                sacc[0][nt] = __builtin_amdgcn_mfma_f32_16x16x32_bf16(qf[0][ks], kf, sacc[0][nt], 0, 0, 0);
                sacc[1][nt] = __builtin_amdgcn_mfma_f32_16x16x32_bf16(qf[1][ks], kf, sacc[1][nt], 0, 0, 0);
            }
        }
        __builtin_amdgcn_s_setprio(0);

        // ---- online softmax (deferred l cross-lane reduction) ----
        float alpha_s[2][4];
        #pragma unroll
        for (int mt = 0; mt < 2; ++mt) {
            #pragma unroll
            for (int r = 0; r < 4; ++r) {
                int slot = mt * 4 + r;
                float mx = fmaxf(fmaxf(sacc[mt][0][r], sacc[mt][1][r]),
                                 fmaxf(sacc[mt][2][r], sacc[mt][3][r]));
                #pragma unroll
                for (int off = 1; off < 16; off <<= 1) mx = fmaxf(mx, __shfl_xor(mx, off, 64));
                float mnew = fmaxf(m_i[slot], mx);
                float al = __expf(m_i[slot] - mnew);
                m_i[slot] = mnew;
                float rs = 0.f;
                #pragma unroll
                for (int nt = 0; nt < 4; ++nt) {
                    float pv = __expf(sacc[mt][nt][r] - mnew);
                    sacc[mt][nt][r] = pv;
                    rs += pv;
                }
                l_pl[slot] = l_pl[slot] * al + rs;     // lane-partial row sum
                alpha_s[mt][r] = al;
            }
        }
        #pragma unroll
        for (int mt = 0; mt < 2; ++mt)
            #pragma unroll
            for (int dt = 0; dt < 8; ++dt)
                #pragma unroll
                for (int r = 0; r < 4; ++r) oacc[mt][dt][r] *= alpha_s[mt][r];

        // ---- P -> LDS (wave-private; C-layout -> A-layout) ----
        #pragma unroll
        for (int mt = 0; mt < 2; ++mt)
            #pragma unroll
            for (int nt = 0; nt < 4; ++nt)
                #pragma unroll
                for (int r = 0; r < 4; ++r)
                    Ps[w * 32 * PSTR + (mt * 16 + quad * 4 + r) * PSTR + nt * 16 + m]
                        = f2bf(sacc[mt][nt][r]);

        // B2: V[kt] arrived everywhere; all waves done reading Ks (QK^T consumed).
        asm volatile("s_waitcnt vmcnt(0)\n\ts_barrier" ::: "memory");

        // issue K[kt+1] -> Ks (overlaps PV below)
        if (kt + 1 < 32) {
            const ushort* ksrc = Khead + (size_t)(kt + 1) * 8192;
            #pragma unroll
            for (int i = 0; i < 4; ++i) {
                int cid = t + i * 256;
                __builtin_amdgcn_global_load_lds(
                    (const __attribute__((address_space(1))) unsigned int*)(ksrc + cid * 8),
                    (__attribute__((address_space(3))) unsigned int*)(Ks + cid * 8),
                    16, 0, 0);
            }
        }

        // ---- O += P @ V : 32 MFMA from 16 V-frag + 4 P-frag reads ----
        __builtin_amdgcn_s_setprio(1);
        #pragma unroll
        for (int ks2 = 0; ks2 < 2; ++ks2) {
            bf16x8 pf0 = *(const bf16x8*)&Ps[w * 32 * PSTR + (0 * 16 + m) * PSTR + ks2 * 32 + quad * 8];
            bf16x8 pf1 = *(const bf16x8*)&Ps[w * 32 * PSTR + (1 * 16 + m) * PSTR + ks2 * 32 + quad * 8];
            #pragma unroll
            for (int dt = 0; dt < 8; ++dt) {
                bf16x8 vf = *(const bf16x8*)&Vs[(dt * 16 + m) * 64 + (((ks2 * 4 + quad) ^ (m & 7))) * 8];
                oacc[0][dt] = __builtin_amdgcn_mfma_f32_16x16x32_bf16(pf0, vf, oacc[0][dt], 0, 0, 0);
                oacc[1][dt] = __builtin_amdgcn_mfma_f32_16x16x32_bf16(pf1, vf, oacc[1][dt], 0, 0, 0);
            }
        }
        __builtin_amdgcn_s_setprio(0);
    }

    // ---- epilogue: finish l reduction, normalize, write ----
    #pragma unroll
    for (int s = 0; s < 8; ++s) {
        #pragma unroll
        for (int off = 1; off < 16; off <<= 1) l_pl[s] += __shfl_xor(l_pl[s], off, 64);
        l_pl[s] = 1.0f / l_pl[s];
    }
    #pragma unroll
    for (int mt = 0; mt < 2; ++mt) {
        #pragma unroll
        for (int dt = 0; dt < 8; ++dt) {
            #pragma unroll
            for (int r = 0; r < 4; ++r) {
                int row = qblk * 128 + w * 32 + mt * 16 + quad * 4 + r;
                y[(size_t)(b * LL + row) * EE + h * HD + dt * 16 + m]
                    = f2bf(oacc[mt][dt][r] * l_pl[mt * 4 + r]);
            }
        }
    }
}

extern "C" void kernel_launch(void* const* d_in, const int* in_sizes, int n_in,
                              void* d_out, int out_size, void* d_ws, size_t ws_size,
                              hipStream_t stream) {
    const float* x      = (const float*)d_in[0];
    const int*   pos    = (const int*)d_in[1];
    const float* W_attn = (const float*)d_in[2];
    const float* b_attn = (const float*)d_in[3];
    const float* W_proj = (const float*)d_in[4];
    const float* b_proj = (const float*)d_in[5];
    float* out = (float*)d_out;

    const int M = BB * LL;   // 4096
    // workspace (ushorts), 134.2 MB total with aliasing:
    ushort* xb   = (ushort*)d_ws;                    // [M][E]      16.8 MB  (→ Qt after gemm1)
    ushort* Wat  = xb   + (size_t)M * EE;            // [3E][E]     25.2 MB  (→ yb after prep)
    ushort* Wpt  = Wat  + (size_t)N3E * EE;          // [E][E]       8.4 MB
    ushort* qkvb = Wpt  + (size_t)EE * EE;           // [M][3E]     50.3 MB
    ushort* Kt   = qkvb + (size_t)M * N3E;           // tiles       16.8 MB
    ushort* Vtt  = Kt   + (size_t)M * EE;            // tiles       16.8 MB
    ushort* Qt   = xb;                               // alias (xb dead after gemm1)
    ushort* yb   = Wat;                              // alias (Wat dead after gemm1)

    dim3 blk(256);
    cvt_bf16<<<dim3(M * EE / (256 * 8)), blk, 0, stream>>>(x, xb, M * EE);
    transpose_bf16<<<dim3(N3E / 32, EE / 32), blk, 0, stream>>>(W_attn, Wat, EE, N3E);
    transpose_bf16<<<dim3(EE / 32, EE / 32), blk, 0, stream>>>(W_proj, Wpt, EE, EE);

    gemm_bt_bf16<1><<<dim3(N3E / 128, M / 128), blk, 0, stream>>>(
        xb, Wat, b_attn, qkvb, M, N3E, EE);

    prep_qk<<<dim3(4096), blk, 0, stream>>>(qkvb, pos, Qt, Kt);
    prep_v<<<dim3(4096), blk, 0, stream>>>(qkvb, Vtt);

    flash2<<<dim3(LL / 128, BB * HH), blk, 0, stream>>>(Qt, Kt, Vtt, yb);

    gemm_bt_bf16<0><<<dim3(EE / 128, M / 128), blk, 0, stream>>>(
        yb, Wpt, b_proj, out, M, EE, EE);
}

// Round 2
// 467.439 us; speedup vs baseline: 1.0138x; 1.0138x over previous
//
#include <hip/hip_runtime.h>
#include <math.h>

#define BB 2
#define LL 2048
#define EE 2048
#define HH 16
#define HD 128
#define N3E (3*EE)   // 6144

typedef __attribute__((ext_vector_type(8))) short  bf16x8;
typedef __attribute__((ext_vector_type(4))) float  f32x4;

__device__ __forceinline__ ushort f2bf(float f) {
    union { float f; unsigned u; } v; v.f = f;
    unsigned u = v.u + 0x7FFFu + ((v.u >> 16) & 1u);   // RNE
    return (ushort)(u >> 16);
}
__device__ __forceinline__ float bf2f(ushort u) {
    union { unsigned u; float f; } v; v.u = ((unsigned)u) << 16;
    return v.f;
}

// ---------------- fp32 -> bf16 convert (x) ----------------
__global__ __launch_bounds__(256) void cvt_bf16(const float* __restrict__ in,
                                                ushort* __restrict__ out, int n) {
    int i = (blockIdx.x * 256 + threadIdx.x) * 8;
    float4 a = *(const float4*)(in + i);
    float4 b = *(const float4*)(in + i + 4);
    ushort4 p0 = { f2bf(a.x), f2bf(a.y), f2bf(a.z), f2bf(a.w) };
    ushort4 p1 = { f2bf(b.x), f2bf(b.y), f2bf(b.z), f2bf(b.w) };
    *(ushort4*)(out + i)     = p0;
    *(ushort4*)(out + i + 4) = p1;
}

// ---------------- fp32 [R][C] -> bf16 [C][R] transpose (weights) ----------------
__global__ __launch_bounds__(256) void transpose_bf16(const float* __restrict__ in,
                                                      ushort* __restrict__ out,
                                                      int R, int Ccol) {
    __shared__ float tile[32][33];
    int c0 = blockIdx.x * 32, r0 = blockIdx.y * 32;
    int t = threadIdx.x;
    int lr = t >> 5, lc = t & 31;
    #pragma unroll
    for (int i = 0; i < 4; ++i)
        tile[lr + i * 8][lc] = in[(size_t)(r0 + lr + i * 8) * Ccol + c0 + lc];
    __syncthreads();
    #pragma unroll
    for (int i = 0; i < 4; ++i)
        out[(size_t)(c0 + lr + i * 8) * R + r0 + lc] = f2bf(tile[lc][lr + i * 8]);
}

// ================= 256x256 8-wave deep-pipelined GEMM (T1+T2+T3+T4+T5) =================
// BK=32, ring of 4 K-tile slots per operand (4 x 16KB x 2 = 128 KiB LDS).
// LDS layout per slot: 16 subtiles of [16 rows][32 elems] (1024 B each);
// within a subtile, byte ^= ((r16&8)?32:0)  (st_16x32 swizzle).
// Staging: linear global_load_lds dest; swizzle folded into the GLOBAL source addr.
// Schedule per K-tile T (2 phases):
//   phase A: ds_read A-frags mt0-3 + B-frags nt0-3 (slot T&3); stage A-unit(T+3);
//            barrier; lgkmcnt(0); 16 MFMA; barrier
//   phase B: ds_read A-frags mt4-7; stage B-unit(T+3); vmcnt(8) [tiles T+2,T+3 in
//            flight -> tile T+1 landed]; barrier (collectivizes); lgkmcnt(0);
//            16 MFMA; barrier
template<int WRITE_BF16>
__global__ __launch_bounds__(512, 2) void gemm256_8ph(const ushort* __restrict__ A,
                                                      const ushort* __restrict__ Bt,
                                                      const float* __restrict__ bias,
                                                      void* __restrict__ C,
                                                      int M, int N, int K, int nby) {
    __shared__ __align__(16) ushort Asl[4 * 8192];   // 64 KB (4 slots x 16KB)
    __shared__ __align__(16) ushort Bsl[4 * 8192];   // 64 KB

    const int t    = threadIdx.x;        // 0..511
    const int lane = t & 63;
    const int w    = t >> 6;             // 0..7
    const int m    = lane & 15;
    const int quad = lane >> 4;
    const int wm   = w >> 2;             // 0..1 (M half)
    const int wn   = w & 3;              // 0..3 (N quarter)

    // T1: XCD-bijective swizzle (gridDim.x % 8 == 0)
    const int nwg = gridDim.x;
    const int cpx = nwg >> 3;
    const int swz = ((int)blockIdx.x & 7) * cpx + ((int)blockIdx.x >> 3);
    const int by  = swz % nby;
    const int bx  = swz / nby;
    const int m0  = by * 256, n0 = bx * 256;

    // staging decomposition (thread t, unit load i=0/1): LDS byte (i*512+t)*16
    //   rg = (i*512+t)>>6, r16 = (t>>2)&15, phys chunk = t&3,
    //   logical chunk = (t&3) ^ ((t&32)?2:0)   [inverse st_16x32]
    const int r16s  = (t >> 2) & 15;
    const int kels  = ((t & 3) ^ ((t & 32) ? 2 : 0)) * 8;   // k element offset 0/8/16/24
    const int row0s = ((t >> 6) << 4) + r16s;               // i=0 row (0..127)
    const int row1s = row0s + 128;                          // i=1 row (128..255)

    // fragment read offset within a subtile (ushorts): swizzled ds_read addr
    const int foff = m * 32 + ((quad * 8) ^ ((m & 8) ? 16 : 0));

#define STAGE_A(T_) do { int _s = (T_) & 3; \
    __builtin_amdgcn_global_load_lds( \
        (const __attribute__((address_space(1))) unsigned int*)(A + (size_t)(m0 + row0s) * K + (T_) * 32 + kels), \
        (__attribute__((address_space(3))) unsigned int*)(Asl + _s * 8192 + t * 8), 16, 0, 0); \
    __builtin_amdgcn_global_load_lds( \
        (const __attribute__((address_space(1))) unsigned int*)(A + (size_t)(m0 + row1s) * K + (T_) * 32 + kels), \
        (__attribute__((address_space(3))) unsigned int*)(Asl + _s * 8192 + (512 + t) * 8), 16, 0, 0); } while (0)
#define STAGE_B(T_) do { int _s = (T_) & 3; \
    __builtin_amdgcn_global_load_lds( \
        (const __attribute__((address_space(1))) unsigned int*)(Bt + (size_t)(n0 + row0s) * K + (T_) * 32 + kels), \
        (__attribute__((address_space(3))) unsigned int*)(Bsl + _s * 8192 + t * 8), 16, 0, 0); \
    __builtin_amdgcn_global_load_lds( \
        (const __attribute__((address_space(1))) unsigned int*)(Bt + (size_t)(n0 + row1s) * K + (T_) * 32 + kels), \
        (__attribute__((address_space(3))) unsigned int*)(Bsl + _s * 8192 + (512 + t) * 8), 16, 0, 0); } while (0)

    f32x4 acc[8][4];
    #pragma unroll
    for (int i = 0; i < 8; ++i)
        #pragma unroll
        for (int j = 0; j < 4; ++j) acc[i][j] = (f32x4){0.f, 0.f, 0.f, 0.f};

    const int NT = K >> 5;               // 64 for K=2048

    // ---- prologue: stage tiles 0,1,2 (12 loads); wait own tile0 (newest 8 = tiles 1,2) ----
    STAGE_A(0); STAGE_B(0);
    STAGE_A(1); STAGE_B(1);
    STAGE_A(2); STAGE_B(2);
    asm volatile("s_waitcnt vmcnt(8)" ::: "memory");
    __builtin_amdgcn_s_barrier();        // collectivize: all waves' tile0 landed

    for (int T = 0; T < NT; ++T) {
        const int slot = T & 3;
        const ushort* as = Asl + slot * 8192 + wm * 4096;   // wm*8 subtiles
        const ushort* bs = Bsl + slot * 8192 + wn * 2048;   // wn*4 subtiles

        // ================= phase A =================
        bf16x8 af[4], bf[4];
        #pragma unroll
        for (int mt = 0; mt < 4; ++mt)
            af[mt] = *(const bf16x8*)(as + mt * 512 + foff);
        #pragma unroll
        for (int nt = 0; nt < 4; ++nt)
            bf[nt] = *(const bf16x8*)(bs + nt * 512 + foff);
        if (T + 3 < NT) STAGE_A(T + 3);
        __builtin_amdgcn_s_barrier();
        asm volatile("s_waitcnt lgkmcnt(0)" ::: "memory");
        __builtin_amdgcn_s_setprio(1);
        #pragma unroll
        for (int mt = 0; mt < 4; ++mt)
            #pragma unroll
            for (int nt = 0; nt < 4; ++nt)
                acc[mt][nt] = __builtin_amdgcn_mfma_f32_16x16x32_bf16(af[mt], bf[nt], acc[mt][nt], 0, 0, 0);
        __builtin_amdgcn_s_setprio(0);
        __builtin_amdgcn_s_barrier();

        // ================= phase B =================
        #pragma unroll
        for (int mt = 0; mt < 4; ++mt)
            af[mt] = *(const bf16x8*)(as + (4 + mt) * 512 + foff);
        if (T + 3 < NT) STAGE_B(T + 3);
        // counted wait: tile T+1 must be landed behind the next barrier.
        if (T + 3 < NT)      asm volatile("s_waitcnt vmcnt(8)" ::: "memory");
        else if (T + 2 < NT) asm volatile("s_waitcnt vmcnt(4)" ::: "memory");
        else                 asm volatile("s_waitcnt vmcnt(0)" ::: "memory");
        __builtin_amdgcn_s_barrier();
        asm volatile("s_waitcnt lgkmcnt(0)" ::: "memory");
        __builtin_amdgcn_s_setprio(1);
        #pragma unroll
        for (int mt = 0; mt < 4; ++mt)
            #pragma unroll
            for (int nt = 0; nt < 4; ++nt)
                acc[4 + mt][nt] = __builtin_amdgcn_mfma_f32_16x16x32_bf16(af[mt], bf[nt], acc[4 + mt][nt], 0, 0, 0);
        __builtin_amdgcn_s_setprio(0);
        __builtin_amdgcn_s_barrier();
    }
#undef STAGE_A
#undef STAGE_B

    // ---- epilogue ----
    float bcol[4];
    #pragma unroll
    for (int nt = 0; nt < 4; ++nt) bcol[nt] = bias[n0 + wn * 64 + nt * 16 + m];
    #pragma unroll
    for (int mt = 0; mt < 8; ++mt) {
        #pragma unroll
        for (int nt = 0; nt < 4; ++nt) {
            #pragma unroll
            for (int r = 0; r < 4; ++r) {
                int row = m0 + wm * 128 + mt * 16 + quad * 4 + r;
                int col = n0 + wn * 64 + nt * 16 + m;
                float v = acc[mt][nt][r] + bcol[nt];
                if (WRITE_BF16) ((ushort*)C)[(size_t)row * N + col] = f2bf(v);
                else            ((float*)C)[(size_t)row * N + col] = v;
            }
        }
    }
}

// ---------------- bf16 MFMA GEMM (m97 structure; used for the 2048-wide proj) ----------------
template<int WRITE_BF16>
__global__ __launch_bounds__(256) void gemm_bt_bf16(const ushort* __restrict__ A,
                                                    const ushort* __restrict__ Bt,
                                                    const float* __restrict__ bias,
                                                    void* __restrict__ C,
                                                    int M, int N, int K) {
    __shared__ __align__(16) ushort As[128 * 32];
    __shared__ __align__(16) ushort Bs[128 * 32];
    const int t    = threadIdx.x;
    const int lane = t & 63, w = t >> 6;
    const int m    = lane & 15, quad = lane >> 4;
    const int wm   = w >> 1, wn = w & 1;
    const int m0   = blockIdx.y * 128, n0 = blockIdx.x * 128;

    f32x4 acc[4][4];
    #pragma unroll
    for (int i = 0; i < 4; ++i)
        #pragma unroll
        for (int j = 0; j < 4; ++j) acc[i][j] = (f32x4){0.f, 0.f, 0.f, 0.f};

    for (int k0 = 0; k0 < K; k0 += 32) {
        __syncthreads();
        #pragma unroll
        for (int i = 0; i < 2; ++i) {
            int c = t + i * 256;
            int row = c >> 2, kc = c & 3;
            __builtin_amdgcn_global_load_lds(
                (const __attribute__((address_space(1))) unsigned int*)(A + (size_t)(m0 + row) * K + k0 + kc * 8),
                (__attribute__((address_space(3))) unsigned int*)(As + c * 8),
                16, 0, 0);
        }
        #pragma unroll
        for (int i = 0; i < 2; ++i) {
            int c = t + i * 256;
            int row = c >> 2, kc = c & 3;
            __builtin_amdgcn_global_load_lds(
                (const __attribute__((address_space(1))) unsigned int*)(Bt + (size_t)(n0 + row) * K + k0 + kc * 8),
                (__attribute__((address_space(3))) unsigned int*)(Bs + c * 8),
                16, 0, 0);
        }
        __syncthreads();
        bf16x8 af[4], bfr[4];
        #pragma unroll
        for (int mt = 0; mt < 4; ++mt)
            af[mt] = *(const bf16x8*)&As[(wm * 64 + mt * 16 + m) * 32 + quad * 8];
        #pragma unroll
        for (int nt = 0; nt < 4; ++nt)
            bfr[nt] = *(const bf16x8*)&Bs[(wn * 64 + nt * 16 + m) * 32 + quad * 8];
        #pragma unroll
        for (int mt = 0; mt < 4; ++mt)
            #pragma unroll
            for (int nt = 0; nt < 4; ++nt)
                acc[mt][nt] = __builtin_amdgcn_mfma_f32_16x16x32_bf16(af[mt], bfr[nt], acc[mt][nt], 0, 0, 0);
    }
    #pragma unroll
    for (int mt = 0; mt < 4; ++mt) {
        #pragma unroll
        for (int nt = 0; nt < 4; ++nt) {
            #pragma unroll
            for (int r = 0; r < 4; ++r) {
                int row = m0 + wm * 64 + mt * 16 + quad * 4 + r;
                int col = n0 + wn * 64 + nt * 16 + m;
                float v = acc[mt][nt][r] + bias[col];
                if (WRITE_BF16) ((ushort*)C)[(size_t)row * N + col] = f2bf(v);
                else            ((float*)C)[(size_t)row * N + col] = v;
            }
        }
    }
}

// ---------------- prep: RoPE + scale + tile/swizzle Q,K ----------------
__global__ __launch_bounds__(256) void prep_qk(const ushort* __restrict__ qkvb,
                                               const int* __restrict__ pos_ids,
                                               ushort* __restrict__ Qt,
                                               ushort* __restrict__ Kt) {
    const float scale = 0.08838834764831845f;
    const float nl2b = -0.20762050593046014f;   // -log2(10000)/64
    int idx = blockIdx.x * 256 + threadIdx.x;   // B*H*32*64*16 = 1048576
    int p    = idx & 15;
    int r    = (idx >> 4) & 63;
    int tile = (idx >> 10) & 31;
    int h    = (idx >> 15) & 15;
    int b    = idx >> 19;
    int c    = p ^ (r & 15);
    int l    = tile * 64 + r;
    int half = c >> 3, cl = c & 7;
    const ushort* row = qkvb + (size_t)(b * LL + l) * N3E;
    float pos = (float)pos_ids[b * LL + l];

    bf16x8 qa = *(const bf16x8*)(row + h * HD + c * 8);
    bf16x8 qb = *(const bf16x8*)(row + h * HD + (c ^ 8) * 8);
    bf16x8 ka = *(const bf16x8*)(row + EE + h * HD + c * 8);
    bf16x8 kb = *(const bf16x8*)(row + EE + h * HD + (c ^ 8) * 8);
    bf16x8 qo, ko;
    #pragma unroll
    for (int i = 0; i < 8; ++i) {
        int j = cl * 8 + i;
        float ang = pos * exp2f((float)j * nl2b);
        float s, cs;
        sincosf(ang, &s, &cs);
        float sgn = half ? s : -s;
        float q1 = bf2f((ushort)qa[i]), q2 = bf2f((ushort)qb[i]);
        float k1 = bf2f((ushort)ka[i]), k2 = bf2f((ushort)kb[i]);
        qo[i] = (short)f2bf((q1 * cs + q2 * sgn) * scale);
        ko[i] = (short)f2bf(k1 * cs + k2 * sgn);
    }
    size_t obase = ((size_t)(b * 16 + h) * 32 + tile) * 8192 + r * 128 + p * 8;
    *(bf16x8*)(Qt + obase) = qo;
    *(bf16x8*)(Kt + obase) = ko;
}

// ---------------- prep: V -> V^T tiles ----------------
__global__ __launch_bounds__(256) void prep_v(const ushort* __restrict__ qkvb,
                                              ushort* __restrict__ Vtt) {
    int idx = blockIdx.x * 256 + threadIdx.x;   // B*H*32*128*8 = 1048576
    int p    = idx & 7;
    int r    = (idx >> 3) & 127;                // d
    int tile = (idx >> 10) & 31;
    int h    = (idx >> 15) & 15;
    int b    = idx >> 19;
    int c    = p ^ (r & 7);
    int col  = 2 * EE + h * HD + r;
    bf16x8 o;
    #pragma unroll
    for (int i = 0; i < 8; ++i) {
        int kk = tile * 64 + c * 8 + i;
        o[i] = (short)qkvb[(size_t)(b * LL + kk) * N3E + col];
    }
    *(bf16x8*)(Vtt + ((size_t)(b * 16 + h) * 32 + tile) * 8192 + r * 64 + p * 8) = o;
}

// ---------------- Flash attention v2: split-barrier pipelined staging ----------------
#define PSTR 68

__global__ __launch_bounds__(256, 2) void flash2(const ushort* __restrict__ Qt,
                                                 const ushort* __restrict__ Kt,
                                                 const ushort* __restrict__ Vtt,
                                                 ushort* __restrict__ y) {
    __shared__ __align__(16) ushort Ks[64 * 128];
    __shared__ __align__(16) ushort Vs[128 * 64];
    __shared__ __align__(16) ushort Ps[4 * 32 * PSTR];

    const int t    = threadIdx.x;
    const int w    = t >> 6;
    const int lane = t & 63;
    const int m    = lane & 15;
    const int quad = lane >> 4;
    const int qblk = blockIdx.x;
    const int bh   = blockIdx.y;
    const int b    = bh >> 4, h = bh & 15;

    const ushort* Qhead = Qt  + (size_t)bh * 32 * 8192;
    const ushort* Khead = Kt  + (size_t)bh * 32 * 8192;
    const ushort* Vhead = Vtt + (size_t)bh * 32 * 8192;

    bf16x8 qf[2][4];
    #pragma unroll
    for (int mt = 0; mt < 2; ++mt) {
        int rloc = w * 32 + mt * 16 + m;
        const ushort* qtile = Qhead + (size_t)(qblk * 2 + (rloc >> 6)) * 8192
                              + (rloc & 63) * 128;
        #pragma unroll
        for (int ks = 0; ks < 4; ++ks)
            qf[mt][ks] = *(const bf16x8*)(qtile + ((ks * 4 + quad) ^ m) * 8);
    }

    f32x4 oacc[2][8];
    #pragma unroll
    for (int mt = 0; mt < 2; ++mt)
        #pragma unroll
        for (int dt = 0; dt < 8; ++dt) oacc[mt][dt] = (f32x4){0.f, 0.f, 0.f, 0.f};
    float m_i[8], l_pl[8];
    #pragma unroll
    for (int s = 0; s < 8; ++s) { m_i[s] = -INFINITY; l_pl[s] = 0.f; }

    {
        const ushort* ksrc = Khead;
        #pragma unroll
        for (int i = 0; i < 4; ++i) {
            int cid = t + i * 256;
            __builtin_amdgcn_global_load_lds(
                (const __attribute__((address_space(1))) unsigned int*)(ksrc + cid * 8),
                (__attribute__((address_space(3))) unsigned int*)(Ks + cid * 8),
                16, 0, 0);
        }
    }

    for (int kt = 0; kt < 32; ++kt) {
        asm volatile("s_waitcnt vmcnt(0)\n\ts_barrier" ::: "memory");

        {
            const ushort* vsrc = Vhead + (size_t)kt * 8192;
            #pragma unroll
            for (int i = 0; i < 4; ++i) {
                int cid = t + i * 256;
                __builtin_amdgcn_global_load_lds(
                    (const __attribute__((address_space(1))) unsigned int*)(vsrc + cid * 8),
                    (__attribute__((address_space(3))) unsigned int*)(Vs + cid * 8),
                    16, 0, 0);
            }
        }

        f32x4 sacc[2][4];
        #pragma unroll
        for (int mt = 0; mt < 2; ++mt)
            #pragma unroll
            for (int nt = 0; nt < 4; ++nt) sacc[mt][nt] = (f32x4){0.f, 0.f, 0.f, 0.f};
        __builtin_amdgcn_s_setprio(1);
        #pragma unroll
        for (int ks = 0; ks < 4; ++ks) {
            #pragma unroll
            for (int nt = 0; nt < 4; ++nt) {
                bf16x8 kf = *(const bf16x8*)&Ks[(nt * 16 + m) * 128 + (((ks * 4 + quad) ^ m)) * 8];
                sacc[0][nt] = __builtin_amdgcn_mfma_f32_16x16x32_bf16(qf[0][ks], kf, sacc[0][nt], 0, 0, 0);
                sacc[1][nt] = __builtin_amdgcn_mfma_f32_16x16x32_bf16(qf[1][ks], kf, sacc[1][nt], 0, 0, 0);
            }
        }
        __builtin_amdgcn_s_setprio(0);

        float alpha_s[2][4];
        #pragma unroll
        for (int mt = 0; mt < 2; ++mt) {
            #pragma unroll
            for (int r = 0; r < 4; ++r) {
                int slot = mt * 4 + r;
                float mx = fmaxf(fmaxf(sacc[mt][0][r], sacc[mt][1][r]),
                                 fmaxf(sacc[mt][2][r], sacc[mt][3][r]));
                #pragma unroll
                for (int off = 1; off < 16; off <<= 1) mx = fmaxf(mx, __shfl_xor(mx, off, 64));
                float mnew = fmaxf(m_i[slot], mx);
                float al = __expf(m_i[slot] - mnew);
                m_i[slot] = mnew;
                float rs = 0.f;
                #pragma unroll
                for (int nt = 0; nt < 4; ++nt) {
                    float pv = __expf(sacc[mt][nt][r] - mnew);
                    sacc[mt][nt][r] = pv;
                    rs += pv;
                }
                l_pl[slot] = l_pl[slot] * al + rs;
                alpha_s[mt][r] = al;
            }
        }
        #pragma unroll
        for (int mt = 0; mt < 2; ++mt)
            #pragma unroll
            for (int dt = 0; dt < 8; ++dt)
                #pragma unroll
                for (int r = 0; r < 4; ++r) oacc[mt][dt][r] *= alpha_s[mt][r];

        #pragma unroll
        for (int mt = 0; mt < 2; ++mt)
            #pragma unroll
            for (int nt = 0; nt < 4; ++nt)
                #pragma unroll
                for (int r = 0; r < 4; ++r)
                    Ps[w * 32 * PSTR + (mt * 16 + quad * 4 + r) * PSTR + nt * 16 + m]
                        = f2bf(sacc[mt][nt][r]);

        asm volatile("s_waitcnt vmcnt(0)\n\ts_barrier" ::: "memory");

        if (kt + 1 < 32) {
            const ushort* ksrc = Khead + (size_t)(kt + 1) * 8192;
            #pragma unroll
            for (int i = 0; i < 4; ++i) {
                int cid = t + i * 256;
                __builtin_amdgcn_global_load_lds(
                    (const __attribute__((address_space(1))) unsigned int*)(ksrc + cid * 8),
                    (__attribute__((address_space(3))) unsigned int*)(Ks + cid * 8),
                    16, 0, 0);
            }
        }

        __builtin_amdgcn_s_setprio(1);
        #pragma unroll
        for (int ks2 = 0; ks2 < 2; ++ks2) {
            bf16x8 pf0 = *(const bf16x8*)&Ps[w * 32 * PSTR + (0 * 16 + m) * PSTR + ks2 * 32 + quad * 8];
            bf16x8 pf1 = *(const bf16x8*)&Ps[w * 32 * PSTR + (1 * 16 + m) * PSTR + ks2 * 32 + quad * 8];
            #pragma unroll
            for (int dt = 0; dt < 8; ++dt) {
                bf16x8 vf = *(const bf16x8*)&Vs[(dt * 16 + m) * 64 + (((ks2 * 4 + quad) ^ (m & 7))) * 8];
                oacc[0][dt] = __builtin_amdgcn_mfma_f32_16x16x32_bf16(pf0, vf, oacc[0][dt], 0, 0, 0);
                oacc[1][dt] = __builtin_amdgcn_mfma_f32_16x16x32_bf16(pf1, vf, oacc[1][dt], 0, 0, 0);
            }
        }
        __builtin_amdgcn_s_setprio(0);
    }

    #pragma unroll
    for (int s = 0; s < 8; ++s) {
        #pragma unroll
        for (int off = 1; off < 16; off <<= 1) l_pl[s] += __shfl_xor(l_pl[s], off, 64);
        l_pl[s] = 1.0f / l_pl[s];
    }
    #pragma unroll
    for (int mt = 0; mt < 2; ++mt) {
        #pragma unroll
        for (int dt = 0; dt < 8; ++dt) {
            #pragma unroll
            for (int r = 0; r < 4; ++r) {
                int row = qblk * 128 + w * 32 + mt * 16 + quad * 4 + r;
                y[(size_t)(b * LL + row) * EE + h * HD + dt * 16 + m]
                    = f2bf(oacc[mt][dt][r] * l_pl[mt * 4 + r]);
            }
        }
    }
}

extern "C" void kernel_launch(void* const* d_in, const int* in_sizes, int n_in,
                              void* d_out, int out_size, void* d_ws, size_t ws_size,
                              hipStream_t stream) {
    const float* x      = (const float*)d_in[0];
    const int*   pos    = (const int*)d_in[1];
    const float* W_attn = (const float*)d_in[2];
    const float* b_attn = (const float*)d_in[3];
    const float* W_proj = (const float*)d_in[4];
    const float* b_proj = (const float*)d_in[5];
    float* out = (float*)d_out;

    const int M = BB * LL;   // 4096
    ushort* xb   = (ushort*)d_ws;                    // [M][E]      (→ Qt after gemm1)
    ushort* Wat  = xb   + (size_t)M * EE;            // [3E][E]     (→ yb after prep)
    ushort* Wpt  = Wat  + (size_t)N3E * EE;          // [E][E]
    ushort* qkvb = Wpt  + (size_t)EE * EE;           // [M][3E]
    ushort* Kt   = qkvb + (size_t)M * N3E;           // tiles
    ushort* Vtt  = Kt   + (size_t)M * EE;            // tiles
    ushort* Qt   = xb;                               // alias
    ushort* yb   = Wat;                              // alias

    dim3 blk(256);
    cvt_bf16<<<dim3(M * EE / (256 * 8)), blk, 0, stream>>>(x, xb, M * EE);
    transpose_bf16<<<dim3(N3E / 32, EE / 32), blk, 0, stream>>>(W_attn, Wat, EE, N3E);
    transpose_bf16<<<dim3(EE / 32, EE / 32), blk, 0, stream>>>(W_proj, Wpt, EE, EE);

    // QKV projection: 256x256 8-phase deep-pipelined GEMM (384 wg, %8==0)
    gemm256_8ph<1><<<dim3((M / 256) * (N3E / 256)), dim3(512), 0, stream>>>(
        xb, Wat, b_attn, qkvb, M, N3E, EE, M / 256);

    prep_qk<<<dim3(4096), blk, 0, stream>>>(qkvb, pos, Qt, Kt);
    prep_v<<<dim3(4096), blk, 0, stream>>>(qkvb, Vtt);

    flash2<<<dim3(LL / 128, BB * HH), blk, 0, stream>>>(Qt, Kt, Vtt, yb);

    gemm_bt_bf16<0><<<dim3(EE / 128, M / 128), blk, 0, stream>>>(
        yb, Wpt, b_proj, out, M, EE, EE);
}

// Round 3
// 458.059 us; speedup vs baseline: 1.0345x; 1.0205x over previous
//
#include <hip/hip_runtime.h>
#include <math.h>

#define BB 2
#define LL 2048
#define EE 2048
#define HH 16
#define HD 128
#define N3E (3*EE)   // 6144

typedef __attribute__((ext_vector_type(8))) short  bf16x8;
typedef __attribute__((ext_vector_type(4))) float  f32x4;

__device__ __forceinline__ ushort f2bf(float f) {
    union { float f; unsigned u; } v; v.f = f;
    unsigned u = v.u + 0x7FFFu + ((v.u >> 16) & 1u);   // RNE
    return (ushort)(u >> 16);
}
__device__ __forceinline__ float bf2f(ushort u) {
    union { unsigned u; float f; } v; v.u = ((unsigned)u) << 16;
    return v.f;
}

// ---------------- fp32 -> bf16 convert (x) ----------------
__global__ __launch_bounds__(256) void cvt_bf16(const float* __restrict__ in,
                                                ushort* __restrict__ out, int n) {
    int i = (blockIdx.x * 256 + threadIdx.x) * 8;
    float4 a = *(const float4*)(in + i);
    float4 b = *(const float4*)(in + i + 4);
    ushort4 p0 = { f2bf(a.x), f2bf(a.y), f2bf(a.z), f2bf(a.w) };
    ushort4 p1 = { f2bf(b.x), f2bf(b.y), f2bf(b.z), f2bf(b.w) };
    *(ushort4*)(out + i)     = p0;
    *(ushort4*)(out + i + 4) = p1;
}

// ---------------- fp32 [R][C] -> bf16 [C][R] transpose (weights) ----------------
__global__ __launch_bounds__(256) void transpose_bf16(const float* __restrict__ in,
                                                      ushort* __restrict__ out,
                                                      int R, int Ccol) {
    __shared__ float tile[32][33];
    int c0 = blockIdx.x * 32, r0 = blockIdx.y * 32;
    int t = threadIdx.x;
    int lr = t >> 5, lc = t & 31;
    #pragma unroll
    for (int i = 0; i < 4; ++i)
        tile[lr + i * 8][lc] = in[(size_t)(r0 + lr + i * 8) * Ccol + c0 + lc];
    __syncthreads();
    #pragma unroll
    for (int i = 0; i < 4; ++i)
        out[(size_t)(c0 + lr + i * 8) * R + r0 + lc] = f2bf(tile[lc][lr + i * 8]);
}

// ================= 256x128 8-wave deep-pipelined GEMM (T1+T2+T3+T4+T5) =================
// BK=32, ring of 4 K-tile slots: A 4x16KB + B 4x8KB = 96 KiB LDS -> 1 block/CU,
// but grid counts are exact multiples of 256 (768 = 3 rounds for gemm1, 256 = 1
// round for gemm2) -> zero dispatch tail (the round-2 killer: 384 blocks = 1.5
// rounds diluted occupancy to 16.5%).
// LDS layout per slot: subtiles of [16 rows][32 elems] (1024 B each); within a
// subtile, 16B-chunk index ^= ((row&8)?2:0)  (st_16x32 swizzle).  Staging keeps
// the global_load_lds DEST linear and folds the inverse swizzle into the GLOBAL
// source address (rule 21); ds_read applies the same swizzle.
// Per K-tile T (single phase, 16 MFMA):
//   ds_read af[4],bf[4] (slot T&3); STAGE(T+3): 3 global_load_lds;
//   vmcnt(6)  [tiles T+2,T+3 in flight -> tile T+1 landed, issued 2 tiles ago];
//   barrier (collectivize); lgkmcnt(0); setprio(1); 16 MFMA; setprio(0); barrier
template<int WRITE_BF16>
__global__ __launch_bounds__(512, 2) void gemm_ktile(const ushort* __restrict__ A,
                                                     const ushort* __restrict__ Bt,
                                                     const float* __restrict__ bias,
                                                     void* __restrict__ C,
                                                     int M, int N, int K, int nby) {
    __shared__ __align__(16) ushort Asl[4 * 8192];   // 64 KB (4 slots x 16KB, 256 rows)
    __shared__ __align__(16) ushort Bsl[4 * 4096];   // 32 KB (4 slots x 8KB, 128 rows)

    const int t    = threadIdx.x;        // 0..511
    const int lane = t & 63;
    const int w    = t >> 6;             // 0..7
    const int m    = lane & 15;
    const int quad = lane >> 4;
    const int wm   = w >> 1;             // 0..3 (M quarter, 64 rows)
    const int wn   = w & 1;              // 0..1 (N half, 64 cols)

    // T1: XCD-bijective swizzle (gridDim.x % 8 == 0)
    const int nwg = gridDim.x;
    const int cpx = nwg >> 3;
    const int swz = ((int)blockIdx.x & 7) * cpx + ((int)blockIdx.x >> 3);
    const int by  = swz % nby;
    const int bx  = swz / nby;
    const int m0  = by * 256, n0 = bx * 128;

    // staging decomposition (thread t): within a slot, chunk c = inst*512 + t,
    //   row = (c>>6)*16 + ((c>>2)&15), phys k-chunk = c&3,
    //   logical k-chunk = (c&3) ^ (((c>>2)&8)?2:0)   [inverse st_16x32]
    const int r16s  = (t >> 2) & 15;
    const int kels  = ((t & 3) ^ ((t & 32) ? 2 : 0)) * 8;   // k elem offset 0/8/16/24
    const int row0s = ((t >> 6) << 4) + r16s;               // rows 0..127
    const int row1s = row0s + 128;                          // rows 128..255 (A only)

    // fragment read offset within a subtile (ushorts): swizzled ds_read addr
    const int foff = m * 32 + ((quad * 8) ^ ((m & 8) ? 16 : 0));

#define STAGE(T_) do { int _s = (T_) & 3; \
    __builtin_amdgcn_global_load_lds( \
        (const __attribute__((address_space(1))) unsigned int*)(A + (size_t)(m0 + row0s) * K + (T_) * 32 + kels), \
        (__attribute__((address_space(3))) unsigned int*)(Asl + _s * 8192 + t * 8), 16, 0, 0); \
    __builtin_amdgcn_global_load_lds( \
        (const __attribute__((address_space(1))) unsigned int*)(A + (size_t)(m0 + row1s) * K + (T_) * 32 + kels), \
        (__attribute__((address_space(3))) unsigned int*)(Asl + _s * 8192 + (512 + t) * 8), 16, 0, 0); \
    __builtin_amdgcn_global_load_lds( \
        (const __attribute__((address_space(1))) unsigned int*)(Bt + (size_t)(n0 + row0s) * K + (T_) * 32 + kels), \
        (__attribute__((address_space(3))) unsigned int*)(Bsl + _s * 4096 + t * 8), 16, 0, 0); } while (0)

    f32x4 acc[4][4];
    #pragma unroll
    for (int i = 0; i < 4; ++i)
        #pragma unroll
        for (int j = 0; j < 4; ++j) acc[i][j] = (f32x4){0.f, 0.f, 0.f, 0.f};

    const int NT = K >> 5;               // 64 for K=2048

    // ---- prologue: stage tiles 0,1,2 (9 loads); wait tile0 (newest 6 = tiles 1,2) ----
    STAGE(0); STAGE(1); STAGE(2);
    asm volatile("s_waitcnt vmcnt(6)" ::: "memory");
    __builtin_amdgcn_s_barrier();        // collectivize: all waves' tile0 landed

    for (int T = 0; T < NT; ++T) {
        const int slot = T & 3;
        const ushort* as = Asl + slot * 8192 + wm * 2048;   // wm*4 subtiles
        const ushort* bs = Bsl + slot * 4096 + wn * 2048;   // wn*4 subtiles

        bf16x8 af[4], bf[4];
        #pragma unroll
        for (int mt = 0; mt < 4; ++mt)
            af[mt] = *(const bf16x8*)(as + mt * 512 + foff);
        #pragma unroll
        for (int nt = 0; nt < 4; ++nt)
            bf[nt] = *(const bf16x8*)(bs + nt * 512 + foff);

        if (T + 3 < NT) STAGE(T + 3);

        // counted wait: tile T+1 must be landed behind the next barrier; loads
        // for it were issued 2 tile-times ago -> latency already covered.
        if (T + 3 < NT)      asm volatile("s_waitcnt vmcnt(6)" ::: "memory");
        else if (T + 2 < NT) asm volatile("s_waitcnt vmcnt(3)" ::: "memory");
        else                 asm volatile("s_waitcnt vmcnt(0)" ::: "memory");
        __builtin_amdgcn_s_barrier();
        asm volatile("s_waitcnt lgkmcnt(0)" ::: "memory");
        __builtin_amdgcn_s_setprio(1);
        #pragma unroll
        for (int mt = 0; mt < 4; ++mt)
            #pragma unroll
            for (int nt = 0; nt < 4; ++nt)
                acc[mt][nt] = __builtin_amdgcn_mfma_f32_16x16x32_bf16(af[mt], bf[nt], acc[mt][nt], 0, 0, 0);
        __builtin_amdgcn_s_setprio(0);
        __builtin_amdgcn_s_barrier();
    }
#undef STAGE

    // ---- epilogue ----
    float bcol[4];
    #pragma unroll
    for (int nt = 0; nt < 4; ++nt) bcol[nt] = bias[n0 + wn * 64 + nt * 16 + m];
    #pragma unroll
    for (int mt = 0; mt < 4; ++mt) {
        #pragma unroll
        for (int nt = 0; nt < 4; ++nt) {
            #pragma unroll
            for (int r = 0; r < 4; ++r) {
                int row = m0 + wm * 64 + mt * 16 + quad * 4 + r;
                int col = n0 + wn * 64 + nt * 16 + m;
                float v = acc[mt][nt][r] + bcol[nt];
                if (WRITE_BF16) ((ushort*)C)[(size_t)row * N + col] = f2bf(v);
                else            ((float*)C)[(size_t)row * N + col] = v;
            }
        }
    }
}

// ---------------- prep: RoPE + scale + tile/swizzle Q,K ----------------
__global__ __launch_bounds__(256) void prep_qk(const ushort* __restrict__ qkvb,
                                               const int* __restrict__ pos_ids,
                                               ushort* __restrict__ Qt,
                                               ushort* __restrict__ Kt) {
    const float scale = 0.08838834764831845f;
    const float nl2b = -0.20762050593046014f;   // -log2(10000)/64
    int idx = blockIdx.x * 256 + threadIdx.x;   // B*H*32*64*16 = 1048576
    int p    = idx & 15;
    int r    = (idx >> 4) & 63;
    int tile = (idx >> 10) & 31;
    int h    = (idx >> 15) & 15;
    int b    = idx >> 19;
    int c    = p ^ (r & 15);
    int l    = tile * 64 + r;
    int half = c >> 3, cl = c & 7;
    const ushort* row = qkvb + (size_t)(b * LL + l) * N3E;
    float pos = (float)pos_ids[b * LL + l];

    bf16x8 qa = *(const bf16x8*)(row + h * HD + c * 8);
    bf16x8 qb = *(const bf16x8*)(row + h * HD + (c ^ 8) * 8);
    bf16x8 ka = *(const bf16x8*)(row + EE + h * HD + c * 8);
    bf16x8 kb = *(const bf16x8*)(row + EE + h * HD + (c ^ 8) * 8);
    bf16x8 qo, ko;
    #pragma unroll
    for (int i = 0; i < 8; ++i) {
        int j = cl * 8 + i;
        float ang = pos * exp2f((float)j * nl2b);
        float s, cs;
        sincosf(ang, &s, &cs);
        float sgn = half ? s : -s;
        float q1 = bf2f((ushort)qa[i]), q2 = bf2f((ushort)qb[i]);
        float k1 = bf2f((ushort)ka[i]), k2 = bf2f((ushort)kb[i]);
        qo[i] = (short)f2bf((q1 * cs + q2 * sgn) * scale);
        ko[i] = (short)f2bf(k1 * cs + k2 * sgn);
    }
    size_t obase = ((size_t)(b * 16 + h) * 32 + tile) * 8192 + r * 128 + p * 8;
    *(bf16x8*)(Qt + obase) = qo;
    *(bf16x8*)(Kt + obase) = ko;
}

// ---------------- prep: V -> V^T tiles ----------------
__global__ __launch_bounds__(256) void prep_v(const ushort* __restrict__ qkvb,
                                              ushort* __restrict__ Vtt) {
    int idx = blockIdx.x * 256 + threadIdx.x;   // B*H*32*128*8 = 1048576
    int p    = idx & 7;
    int r    = (idx >> 3) & 127;                // d
    int tile = (idx >> 10) & 31;
    int h    = (idx >> 15) & 15;
    int b    = idx >> 19;
    int c    = p ^ (r & 7);
    int col  = 2 * EE + h * HD + r;
    bf16x8 o;
    #pragma unroll
    for (int i = 0; i < 8; ++i) {
        int kk = tile * 64 + c * 8 + i;
        o[i] = (short)qkvb[(size_t)(b * LL + kk) * N3E + col];
    }
    *(bf16x8*)(Vtt + ((size_t)(b * 16 + h) * 32 + tile) * 8192 + r * 64 + p * 8) = o;
}

// ---------------- Flash attention v2: split-barrier pipelined staging ----------------
#define PSTR 68

__global__ __launch_bounds__(256, 2) void flash2(const ushort* __restrict__ Qt,
                                                 const ushort* __restrict__ Kt,
                                                 const ushort* __restrict__ Vtt,
                                                 ushort* __restrict__ y) {
    __shared__ __align__(16) ushort Ks[64 * 128];
    __shared__ __align__(16) ushort Vs[128 * 64];
    __shared__ __align__(16) ushort Ps[4 * 32 * PSTR];

    const int t    = threadIdx.x;
    const int w    = t >> 6;
    const int lane = t & 63;
    const int m    = lane & 15;
    const int quad = lane >> 4;
    const int qblk = blockIdx.x;
    const int bh   = blockIdx.y;
    const int b    = bh >> 4, h = bh & 15;

    const ushort* Qhead = Qt  + (size_t)bh * 32 * 8192;
    const ushort* Khead = Kt  + (size_t)bh * 32 * 8192;
    const ushort* Vhead = Vtt + (size_t)bh * 32 * 8192;

    bf16x8 qf[2][4];
    #pragma unroll
    for (int mt = 0; mt < 2; ++mt) {
        int rloc = w * 32 + mt * 16 + m;
        const ushort* qtile = Qhead + (size_t)(qblk * 2 + (rloc >> 6)) * 8192
                              + (rloc & 63) * 128;
        #pragma unroll
        for (int ks = 0; ks < 4; ++ks)
            qf[mt][ks] = *(const bf16x8*)(qtile + ((ks * 4 + quad) ^ m) * 8);
    }

    f32x4 oacc[2][8];
    #pragma unroll
    for (int mt = 0; mt < 2; ++mt)
        #pragma unroll
        for (int dt = 0; dt < 8; ++dt) oacc[mt][dt] = (f32x4){0.f, 0.f, 0.f, 0.f};
    float m_i[8], l_pl[8];
    #pragma unroll
    for (int s = 0; s < 8; ++s) { m_i[s] = -INFINITY; l_pl[s] = 0.f; }

    {
        const ushort* ksrc = Khead;
        #pragma unroll
        for (int i = 0; i < 4; ++i) {
            int cid = t + i * 256;
            __builtin_amdgcn_global_load_lds(
                (const __attribute__((address_space(1))) unsigned int*)(ksrc + cid * 8),
                (__attribute__((address_space(3))) unsigned int*)(Ks + cid * 8),
                16, 0, 0);
        }
    }

    for (int kt = 0; kt < 32; ++kt) {
        asm volatile("s_waitcnt vmcnt(0)\n\ts_barrier" ::: "memory");

        {
            const ushort* vsrc = Vhead + (size_t)kt * 8192;
            #pragma unroll
            for (int i = 0; i < 4; ++i) {
                int cid = t + i * 256;
                __builtin_amdgcn_global_load_lds(
                    (const __attribute__((address_space(1))) unsigned int*)(vsrc + cid * 8),
                    (__attribute__((address_space(3))) unsigned int*)(Vs + cid * 8),
                    16, 0, 0);
            }
        }

        f32x4 sacc[2][4];
        #pragma unroll
        for (int mt = 0; mt < 2; ++mt)
            #pragma unroll
            for (int nt = 0; nt < 4; ++nt) sacc[mt][nt] = (f32x4){0.f, 0.f, 0.f, 0.f};
        __builtin_amdgcn_s_setprio(1);
        #pragma unroll
        for (int ks = 0; ks < 4; ++ks) {
            #pragma unroll
            for (int nt = 0; nt < 4; ++nt) {
                bf16x8 kf = *(const bf16x8*)&Ks[(nt * 16 + m) * 128 + (((ks * 4 + quad) ^ m)) * 8];
                sacc[0][nt] = __builtin_amdgcn_mfma_f32_16x16x32_bf16(qf[0][ks], kf, sacc[0][nt], 0, 0, 0);
                sacc[1][nt] = __builtin_amdgcn_mfma_f32_16x16x32_bf16(qf[1][ks], kf, sacc[1][nt], 0, 0, 0);
            }
        }
        __builtin_amdgcn_s_setprio(0);

        float alpha_s[2][4];
        #pragma unroll
        for (int mt = 0; mt < 2; ++mt) {
            #pragma unroll
            for (int r = 0; r < 4; ++r) {
                int slot = mt * 4 + r;
                float mx = fmaxf(fmaxf(sacc[mt][0][r], sacc[mt][1][r]),
                                 fmaxf(sacc[mt][2][r], sacc[mt][3][r]));
                #pragma unroll
                for (int off = 1; off < 16; off <<= 1) mx = fmaxf(mx, __shfl_xor(mx, off, 64));
                float mnew = fmaxf(m_i[slot], mx);
                float al = __expf(m_i[slot] - mnew);
                m_i[slot] = mnew;
                float rs = 0.f;
                #pragma unroll
                for (int nt = 0; nt < 4; ++nt) {
                    float pv = __expf(sacc[mt][nt][r] - mnew);
                    sacc[mt][nt][r] = pv;
                    rs += pv;
                }
                l_pl[slot] = l_pl[slot] * al + rs;
                alpha_s[mt][r] = al;
            }
        }
        #pragma unroll
        for (int mt = 0; mt < 2; ++mt)
            #pragma unroll
            for (int dt = 0; dt < 8; ++dt)
                #pragma unroll
                for (int r = 0; r < 4; ++r) oacc[mt][dt][r] *= alpha_s[mt][r];

        #pragma unroll
        for (int mt = 0; mt < 2; ++mt)
            #pragma unroll
            for (int nt = 0; nt < 4; ++nt)
                #pragma unroll
                for (int r = 0; r < 4; ++r)
                    Ps[w * 32 * PSTR + (mt * 16 + quad * 4 + r) * PSTR + nt * 16 + m]
                        = f2bf(sacc[mt][nt][r]);

        asm volatile("s_waitcnt vmcnt(0)\n\ts_barrier" ::: "memory");

        if (kt + 1 < 32) {
            const ushort* ksrc = Khead + (size_t)(kt + 1) * 8192;
            #pragma unroll
            for (int i = 0; i < 4; ++i) {
                int cid = t + i * 256;
                __builtin_amdgcn_global_load_lds(
                    (const __attribute__((address_space(1))) unsigned int*)(ksrc + cid * 8),
                    (__attribute__((address_space(3))) unsigned int*)(Ks + cid * 8),
                    16, 0, 0);
            }
        }

        __builtin_amdgcn_s_setprio(1);
        #pragma unroll
        for (int ks2 = 0; ks2 < 2; ++ks2) {
            bf16x8 pf0 = *(const bf16x8*)&Ps[w * 32 * PSTR + (0 * 16 + m) * PSTR + ks2 * 32 + quad * 8];
            bf16x8 pf1 = *(const bf16x8*)&Ps[w * 32 * PSTR + (1 * 16 + m) * PSTR + ks2 * 32 + quad * 8];
            #pragma unroll
            for (int dt = 0; dt < 8; ++dt) {
                bf16x8 vf = *(const bf16x8*)&Vs[(dt * 16 + m) * 64 + (((ks2 * 4 + quad) ^ (m & 7))) * 8];
                oacc[0][dt] = __builtin_amdgcn_mfma_f32_16x16x32_bf16(pf0, vf, oacc[0][dt], 0, 0, 0);
                oacc[1][dt] = __builtin_amdgcn_mfma_f32_16x16x32_bf16(pf1, vf, oacc[1][dt], 0, 0, 0);
            }
        }
        __builtin_amdgcn_s_setprio(0);
    }

    #pragma unroll
    for (int s = 0; s < 8; ++s) {
        #pragma unroll
        for (int off = 1; off < 16; off <<= 1) l_pl[s] += __shfl_xor(l_pl[s], off, 64);
        l_pl[s] = 1.0f / l_pl[s];
    }
    #pragma unroll
    for (int mt = 0; mt < 2; ++mt) {
        #pragma unroll
        for (int dt = 0; dt < 8; ++dt) {
            #pragma unroll
            for (int r = 0; r < 4; ++r) {
                int row = qblk * 128 + w * 32 + mt * 16 + quad * 4 + r;
                y[(size_t)(b * LL + row) * EE + h * HD + dt * 16 + m]
                    = f2bf(oacc[mt][dt][r] * l_pl[mt * 4 + r]);
            }
        }
    }
}

extern "C" void kernel_launch(void* const* d_in, const int* in_sizes, int n_in,
                              void* d_out, int out_size, void* d_ws, size_t ws_size,
                              hipStream_t stream) {
    const float* x      = (const float*)d_in[0];
    const int*   pos    = (const int*)d_in[1];
    const float* W_attn = (const float*)d_in[2];
    const float* b_attn = (const float*)d_in[3];
    const float* W_proj = (const float*)d_in[4];
    const float* b_proj = (const float*)d_in[5];
    float* out = (float*)d_out;

    const int M = BB * LL;   // 4096
    ushort* xb   = (ushort*)d_ws;                    // [M][E]      (→ Qt after gemm1)
    ushort* Wat  = xb   + (size_t)M * EE;            // [3E][E]     (→ yb after prep)
    ushort* Wpt  = Wat  + (size_t)N3E * EE;          // [E][E]
    ushort* qkvb = Wpt  + (size_t)EE * EE;           // [M][3E]
    ushort* Kt   = qkvb + (size_t)M * N3E;           // tiles
    ushort* Vtt  = Kt   + (size_t)M * EE;            // tiles
    ushort* Qt   = xb;                               // alias
    ushort* yb   = Wat;                              // alias

    dim3 blk(256);
    cvt_bf16<<<dim3(M * EE / (256 * 8)), blk, 0, stream>>>(x, xb, M * EE);
    transpose_bf16<<<dim3(N3E / 32, EE / 32), blk, 0, stream>>>(W_attn, Wat, EE, N3E);
    transpose_bf16<<<dim3(EE / 32, EE / 32), blk, 0, stream>>>(W_proj, Wpt, EE, EE);

    // QKV projection: 256x128 tiles -> 16*48 = 768 wg = exactly 3 rounds @ 1/CU
    gemm_ktile<1><<<dim3((M / 256) * (N3E / 128)), dim3(512), 0, stream>>>(
        xb, Wat, b_attn, qkvb, M, N3E, EE, M / 256);

    prep_qk<<<dim3(4096), blk, 0, stream>>>(qkvb, pos, Qt, Kt);
    prep_v<<<dim3(4096), blk, 0, stream>>>(qkvb, Vtt);

    flash2<<<dim3(LL / 128, BB * HH), blk, 0, stream>>>(Qt, Kt, Vtt, yb);

    // out projection: 16*16 = 256 wg = exactly 1 round
    gemm_ktile<0><<<dim3((M / 256) * (EE / 128)), dim3(512), 0, stream>>>(
        yb, Wpt, b_proj, out, M, EE, EE, M / 256);
}